// Round 9
// baseline (340.073 us; speedup 1.0000x reference)
//
#include <hip/hip_runtime.h>

#define H_   256
#define W_   256
#define HW_  65536
#define C_   256
#define MID  16
#define B_   2

// ---------------------------------------------------------------------------
// K0: 4 normalized anisotropic Gaussian 7x7 kernels (196 floats).
// ---------------------------------------------------------------------------
__global__ __launch_bounds__(256) void k0_prep(float* __restrict__ base_out) {
    __shared__ float s_k[4][49];
    __shared__ float s_inv[4];
    int t = threadIdx.x;
    if (t < 196) {
        int k = t / 49, p = t % 49;
        int i = p / 7, j = p % 7;
        float xx = (float)(i - 3), yy = (float)(j - 3);
        const float cs[4] = {1.0f, 0.70710678118654752f, 0.0f, -0.70710678118654752f};
        const float sn[4] = {0.0f, 0.70710678118654752f, 1.0f, 0.70710678118654752f};
        float c = cs[k], s = sn[k];
        float xr = xx * c + yy * s;
        float yr = -xx * s + yy * c;
        float v = expf(-(xr * xr * 0.08f + yr * yr * 0.5f));
        s_k[k][p] = v;
    }
    __syncthreads();
    if (t < 4) {
        float s = 0.f;
        for (int p = 0; p < 49; ++p) s += s_k[t][p];
        s_inv[t] = 1.0f / s;
    }
    __syncthreads();
    if (t < 196) base_out[t] = s_k[t / 49][t % 49] * s_inv[t / 49];
}

// ---------------------------------------------------------------------------
// kA: partial channel reduction, c-split 4, 4 px/thread via float4
// (16 B/lane = 1 KB/wave-request; R6/R8 A-B showed 4B->8B loads halved time
// on this 256KB-strided stream -> width is the lever, go 16B).
// 512 blocks = cq(4) x b(2) x rowgroup(64); 256 thr; 8 waves/CU.
// Depth-8 float4 pipeline (32 VGPR) + 16 float4 acc (64 VGPR) ~ 106 VGPR.
// part[(cq*2+b)*MID + m][hw] planar.
// ---------------------------------------------------------------------------
__global__ __launch_bounds__(256, 2) void kA_reduce(const float* __restrict__ x,
                                                    const float* __restrict__ rw,
                                                    float* __restrict__ part) {
    int bid = blockIdx.x;
    int cq = bid & 3;
    int b = (bid >> 2) & 1;
    int rg = bid >> 3;               // 0..63
    int t = threadIdx.x;
    int px0 = rg * 1024 + t * 4;
    const float4* xp = (const float4*)(x + (size_t)b * C_ * HW_ + (size_t)cq * 64 * HW_ + px0);
    const float* wp = rw + cq * 64;
    float4 acc[MID];
#pragma unroll
    for (int m = 0; m < MID; ++m) acc[m] = make_float4(0.f, 0.f, 0.f, 0.f);
    for (int cb = 0; cb < 64; cb += 8) {
        float4 xv[8];
#pragma unroll
        for (int i = 0; i < 8; ++i)
            xv[i] = xp[(size_t)(cb + i) * (HW_ / 4)];
#pragma unroll
        for (int i = 0; i < 8; ++i) {
#pragma unroll
            for (int m = 0; m < MID; ++m) {
                float wv = wp[m * C_ + cb + i];   // uniform -> s_load
                acc[m].x = fmaf(wv, xv[i].x, acc[m].x);
                acc[m].y = fmaf(wv, xv[i].y, acc[m].y);
                acc[m].z = fmaf(wv, xv[i].z, acc[m].z);
                acc[m].w = fmaf(wv, xv[i].w, acc[m].w);
            }
        }
    }
    float4* op = (float4*)(part + ((size_t)(cq * 2 + b) * MID) * HW_ + px0);
#pragma unroll
    for (int m = 0; m < MID; ++m) op[m * (HW_ / 4)] = acc[m];
}

// ---------------------------------------------------------------------------
// kS: xlow = sum of 4 partials (planar float4 stream, 42 MB total).
// 2048 blocks x 256 thr.
// ---------------------------------------------------------------------------
__global__ __launch_bounds__(256) void kS_sum(const float* __restrict__ part,
                                              float* __restrict__ xlow) {
    size_t i = (size_t)blockIdx.x * 256 + threadIdx.x;   // float4 index
    const size_t stride = (size_t)B_ * MID * HW_ / 4;    // 524288
    const float4* p = (const float4*)part;
    float4 a = p[i];
    float4 b = p[i + stride];
    float4 c = p[i + 2 * stride];
    float4 d = p[i + 3 * stride];
    float4 r;
    r.x = (a.x + b.x) + (c.x + d.x);
    r.y = (a.y + b.y) + (c.y + d.y);
    r.z = (a.z + b.z) + (c.z + d.z);
    r.w = (a.w + b.w) + (c.w + d.w);
    ((float4*)xlow)[i] = r;
}

// ---------------------------------------------------------------------------
// kB: per-pixel MLP -> softmax -> 49 blended taps in registers -> gather
// conv over 8 planar channels (m-half per block) -> PLANAR olow stores.
// 1024 blocks = b(2) x h(256) x mh(2); 16 waves/CU.
// ---------------------------------------------------------------------------
__global__ __launch_bounds__(256, 4) void kB_conv(const float* __restrict__ xlow,
                                                  const float* __restrict__ base,
                                                  const float* __restrict__ angle,
                                                  const float* __restrict__ w1,
                                                  const float* __restrict__ b1,
                                                  const float* __restrict__ w2,
                                                  const float* __restrict__ b2,
                                                  float* __restrict__ olow) {
    int bid = blockIdx.x;
    int mh = bid & 1;
    int h = (bid >> 1) & 255;
    int b = bid >> 9;
    int w = threadIdx.x;

    // ---- MLP + softmax -> wk[4] ----
    float a2 = 2.0f * angle[(size_t)b * HW_ + h * W_ + w];
    float f0 = __sinf(a2), f1 = __cosf(a2);
    float hb[8];
#pragma unroll
    for (int j = 0; j < 8; ++j)
        hb[j] = fmaxf(fmaf(w1[j * 2], f0, fmaf(w1[j * 2 + 1], f1, b1[j])), 0.f);
    float lg[4];
#pragma unroll
    for (int k = 0; k < 4; ++k) {
        float s = b2[k];
#pragma unroll
        for (int j = 0; j < 8; ++j) s = fmaf(w2[k * 8 + j], hb[j], s);
        lg[k] = s;
    }
    float mx = fmaxf(fmaxf(lg[0], lg[1]), fmaxf(lg[2], lg[3]));
    float wk[4];
    float ssum = 0.f;
#pragma unroll
    for (int k = 0; k < 4; ++k) { wk[k] = __expf(lg[k] - mx); ssum += wk[k]; }
    float inv = 1.0f / ssum;
#pragma unroll
    for (int k = 0; k < 4; ++k) wk[k] *= inv;

    // ---- blended taps into registers ----
    float e[49];
#pragma unroll
    for (int tp = 0; tp < 49; ++tp)
        e[tp] = fmaf(wk[0], base[tp],
                fmaf(wk[1], base[49 + tp],
                fmaf(wk[2], base[98 + tp], wk[3] * base[147 + tp])));

    // ---- reflect indices ----
    int cc[7];
#pragma unroll
    for (int dx = 0; dx < 7; ++dx) {
        int c0 = w + dx - 3;
        cc[dx] = c0 < 0 ? -c0 : (c0 > 255 ? 510 - c0 : c0);
    }
    int rr[7];
#pragma unroll
    for (int dy = 0; dy < 7; ++dy) {
        int hy = h + dy - 3;
        rr[dy] = (hy < 0 ? -hy : (hy > 255 ? 510 - hy : hy)) * W_;
    }

    // ---- conv: 8 planes, m-outer ----
    const float* xb = xlow + (size_t)b * MID * HW_ + (size_t)mh * 8 * HW_;
    float acc[8];
#pragma unroll
    for (int m = 0; m < 8; ++m) {
        const float* pm = xb + (size_t)m * HW_;
        float s = 0.f;
#pragma unroll
        for (int dy = 0; dy < 7; ++dy) {
            const float* r = pm + rr[dy];
#pragma unroll
            for (int dx = 0; dx < 7; ++dx)
                s = fmaf(e[dy * 7 + dx], r[cc[dx]], s);
        }
        acc[m] = s;
    }

    // ---- planar stores (coalesced dwords) ----
    float* op = olow + ((size_t)b * MID + mh * 8) * HW_ + h * W_ + w;
#pragma unroll
    for (int m = 0; m < 8; ++m) op[(size_t)m * HW_] = acc[m];
}

// ---------------------------------------------------------------------------
// kC: expand 16->256 from PLANAR olow (16 coalesced dword loads), c-split 4,
// 2048 blocks = 32 waves/CU, 64 nt dword stores.
// ---------------------------------------------------------------------------
__global__ __launch_bounds__(256) void kC_expand(const float* __restrict__ olow,
                                                 const float* __restrict__ ew,
                                                 float* __restrict__ out) {
    int bid = blockIdx.x;
    int cq = bid & 3;
    int h = (bid >> 2) & 255;
    int b = bid >> 10;
    int w = threadIdx.x;
    const float* ip = olow + (size_t)b * MID * HW_ + h * W_ + w;
    float mv[MID];
#pragma unroll
    for (int m = 0; m < MID; ++m) mv[m] = ip[(size_t)m * HW_];
    float* ob = out + ((size_t)b * C_ + cq * 64) * HW_ + h * W_ + w;
    const float* wb = ew + (size_t)cq * 64 * MID;
#pragma unroll 8
    for (int ci = 0; ci < 64; ++ci) {
        const float* wc = wb + ci * MID;
        float s = wc[0] * mv[0];
#pragma unroll
        for (int m = 1; m < MID; ++m) s = fmaf(wc[m], mv[m], s);
        __builtin_nontemporal_store(s, ob + (size_t)ci * HW_);
    }
}

// ---------------------------------------------------------------------------
extern "C" void kernel_launch(void* const* d_in, const int* in_sizes, int n_in,
                              void* d_out, int out_size, void* d_ws, size_t ws_size,
                              hipStream_t stream) {
    const float* x     = (const float*)d_in[0];
    const float* angle = (const float*)d_in[1];
    const float* rw    = (const float*)d_in[2];
    const float* ew    = (const float*)d_in[3];
    const float* w1    = (const float*)d_in[4];
    const float* b1    = (const float*)d_in[5];
    const float* w2    = (const float*)d_in[6];
    const float* b2    = (const float*)d_in[7];
    float* out = (float*)d_out;

    float* wsf  = (float*)d_ws;
    float* base = wsf;                               // 196 floats
    float* xlow = wsf + 256;                         // 2M floats, planar
    float* olow = xlow + (size_t)B_ * MID * HW_;     // 2M floats, planar
    float* part = olow + (size_t)B_ * MID * HW_;     // 8.4M floats

    hipLaunchKernelGGL(k0_prep,   dim3(1),    dim3(256), 0, stream, base);
    hipLaunchKernelGGL(kA_reduce, dim3(512),  dim3(256), 0, stream, x, rw, part);
    hipLaunchKernelGGL(kS_sum,    dim3(2048), dim3(256), 0, stream, part, xlow);
    hipLaunchKernelGGL(kB_conv,   dim3(1024), dim3(256), 0, stream,
                       xlow, base, angle, w1, b1, w2, b2, olow);
    hipLaunchKernelGGL(kC_expand, dim3(2048), dim3(256), 0, stream, olow, ew, out);
}